// Round 1
// baseline (427.971 us; speedup 1.0000x reference)
//
#include <hip/hip_runtime.h>
#include <hip/hip_bf16.h>

typedef __attribute__((ext_vector_type(4))) float f32x4;
typedef __attribute__((ext_vector_type(8))) short bf16x8;
typedef unsigned int   u32;
typedef unsigned short u16;

#define DPAD 8
#define B_   8
#define C_   512
#define T_   8192
#define S_   256

// workspace byte offsets
#define OFF_WBIG 0u          // u16[1024*1024]      = 2,097,152 B
#define OFF_W2   2097152u    // u16[768*512]        =   786,432 B
#define OFF_B1   2883584u    // float[1024]
#define OFF_B2   2887680u    // float[768]
#define OFF_XT   2891776u    // u16[8*(8192+8)*512] = 67,174,400 B
#define OFF_ZT   70066176u   // u16[8*8192*512]     = 67,108,864 B

__device__ __forceinline__ u16 f2bf(float f) {
  u32 u = __builtin_bit_cast(u32, f);
  u += 0x7FFFu + ((u >> 16) & 1u);
  return (u16)(u >> 16);
}
__device__ __forceinline__ float sigm_(float x) { return 1.0f / (1.0f + __expf(-x)); }
__device__ __forceinline__ float tanh_(float x) { return 2.0f / (1.0f + __expf(-2.0f * x)) - 1.0f; }

__device__ __forceinline__ void gload_lds16(const void* g, void* l) {
  __builtin_amdgcn_global_load_lds(
      (const __attribute__((address_space(1))) void*)g,
      (__attribute__((address_space(3))) void*)l, 16, 0, 0);
}

// ---------------- pack weights / biases, zero Xt pad rows ----------------
__global__ void pack_kernel(const float* __restrict__ fw, const float* __restrict__ fb,
                            const float* __restrict__ gw, const float* __restrict__ gb,
                            const float* __restrict__ rw, const float* __restrict__ rb,
                            const float* __restrict__ sw, const float* __restrict__ sb,
                            u16* __restrict__ Wbig, u16* __restrict__ W2,
                            float* __restrict__ b1, float* __restrict__ b2,
                            u16* __restrict__ Xt)
{
  int idx = blockIdx.x * 256 + threadIdx.x;
  if (idx < 1048576) {                    // Wbig[row][k], row 2i=filter i, 2i+1=gate i
    int row = idx >> 10, k = idx & 1023;  // k<512: tap1 (x[t]); k>=512: tap0 (x[t-d])
    int i = row >> 1;
    const float* src = (row & 1) ? gw : fw;
    float v = src[((i << 9) + (k & 511)) * 2 + ((k < 512) ? 1 : 0)];
    Wbig[idx] = f2bf(v);
    return;
  }
  idx -= 1048576;
  if (idx < 393216) {                     // W2[r][k]: r<512 res, else skip
    int r = idx >> 9, k = idx & 511;
    float v = (r < 512) ? rw[(r << 9) + k] : sw[((r - 512) << 9) + k];
    W2[idx] = f2bf(v);
    return;
  }
  idx -= 393216;
  if (idx < 1024) { b1[idx] = (idx & 1) ? gb[idx >> 1] : fb[idx >> 1]; return; }
  idx -= 1024;
  if (idx < 768) { b2[idx] = (idx < 512) ? rb[idx] : sb[idx - 512]; return; }
  idx -= 768;
  if (idx < B_ * DPAD * C_) {             // zero causal pad rows of Xt
    int b = idx >> 12;                    // DPAD*C_ = 4096
    int rest = idx & 4095;
    Xt[(size_t)b * (T_ + DPAD) * C_ + rest] = 0;
  }
}

// ---------------- x [B][C][T] f32 -> Xt [B][DPAD+T][C] bf16 ----------------
__global__ __launch_bounds__(256) void transpose_kernel(const float* __restrict__ x,
                                                        u16* __restrict__ Xt)
{
  __shared__ float tile[64][65];
  int bid = blockIdx.x;
  int ct = bid & 7, tt = (bid >> 3) & 127, b = bid >> 10;
  int w = threadIdx.x >> 6, ln = threadIdx.x & 63;
  const float* xp = x + ((size_t)(b * C_ + ct * 64)) * T_ + tt * 64;
#pragma unroll
  for (int r = 0; r < 16; ++r) {
    int cl = r * 4 + w;
    tile[cl][ln] = xp[(size_t)cl * T_ + ln];
  }
  __syncthreads();
  u16* op = Xt + ((size_t)b * (T_ + DPAD) + DPAD + tt * 64) * C_ + ct * 64;
#pragma unroll
  for (int r = 0; r < 16; ++r) {
    int tl = r * 4 + w;
    op[(size_t)tl * C_ + ln] = f2bf(tile[ln][tl]);
  }
}

// ---------------- GEMM1: [1024x1024] x [1024 x 65536] + gated activation ----------------
__global__ __launch_bounds__(256, 2) void gemm1_kernel(
    const u16* __restrict__ W, const u16* __restrict__ Xt,
    const float* __restrict__ b1, u16* __restrict__ Zt,
    const int* __restrict__ dptr)
{
  __shared__ __align__(16) u16 As[128 * 32];
  __shared__ __align__(16) u16 Bs[128 * 32];
  const int d = *dptr;
  const int tid = threadIdx.x;
  const int lane = tid & 63, wave = tid >> 6;
  const int wm = wave >> 1, wn = wave & 1;
  const int m0 = blockIdx.x * 128;
  const int n0g = blockIdx.y * 128;
  const int b = n0g >> 13, t0 = n0g & (T_ - 1);
  const int srow = tid >> 2;          // 0..63
  const int skk  = (tid & 3) * 8;     // 0,8,16,24

  f32x4 acc[4][4];
#pragma unroll
  for (int i = 0; i < 4; ++i)
#pragma unroll
    for (int j = 0; j < 4; ++j) acc[i][j] = (f32x4){0.f, 0.f, 0.f, 0.f};

  const int aoff = (wm * 64 + (lane & 15)) * 32 + (lane >> 4) * 8;
  const int boff = (wn * 64 + (lane & 15)) * 32 + (lane >> 4) * 8;
  const size_t xtb = (size_t)b * (T_ + DPAD) * C_;

  for (int kc = 0; kc < 32; ++kc) {
    const int k = kc * 32 + skk;        // 0..1023
    const int col = k & 511;
    const int rsh = (k >= 512) ? d : 0; // tap0 reads t-d rows (pad rows are zero)
    const u16* gA = W + (size_t)(m0 + srow) * 1024 + k;
    const u16* gB = Xt + xtb + (size_t)(DPAD + t0 + srow - rsh) * C_ + col;
    gload_lds16(gA,             As + tid * 8);
    gload_lds16(gA + 64 * 1024, As + 2048 + tid * 8);
    gload_lds16(gB,             Bs + tid * 8);
    gload_lds16(gB + 64 * C_,   Bs + 2048 + tid * 8);
    asm volatile("s_waitcnt vmcnt(0)" ::: "memory");
    __syncthreads();
    bf16x8 af[4], bfr[4];
#pragma unroll
    for (int i = 0; i < 4; ++i) af[i]  = *(const bf16x8*)(As + aoff + i * 512);
#pragma unroll
    for (int j = 0; j < 4; ++j) bfr[j] = *(const bf16x8*)(Bs + boff + j * 512);
#pragma unroll
    for (int i = 0; i < 4; ++i)
#pragma unroll
      for (int j = 0; j < 4; ++j)
        acc[i][j] = __builtin_amdgcn_mfma_f32_16x16x32_bf16(af[i], bfr[j], acc[i][j], 0, 0, 0);
    __syncthreads();
  }

  // epilogue: rows R..R+3 = (filter c0, gate c0, filter c0+1, gate c0+1)
#pragma unroll
  for (int i = 0; i < 4; ++i) {
    const int R = m0 + wm * 64 + i * 16 + ((lane >> 4) << 2);
    const float bi0 = b1[R], bi1 = b1[R + 1], bi2 = b1[R + 2], bi3 = b1[R + 3];
    const int c0 = R >> 1;
#pragma unroll
    for (int j = 0; j < 4; ++j) {
      const int ttc = t0 + wn * 64 + j * 16 + (lane & 15);
      f32x4 v = acc[i][j];
      float z0 = tanh_(v[0] + bi0) * sigm_(v[1] + bi1);
      float z1 = tanh_(v[2] + bi2) * sigm_(v[3] + bi3);
      u32 p = (u32)f2bf(z0) | ((u32)f2bf(z1) << 16);
      *(u32*)(Zt + (size_t)(b * T_ + ttc) * C_ + c0) = p;
    }
  }
}

// ---------------- GEMM2: [768x512] x z + residual/skip epilogue ----------------
__global__ __launch_bounds__(256, 2) void gemm2_kernel(
    const u16* __restrict__ W2, const u16* __restrict__ Zt,
    const float* __restrict__ b2, const float* __restrict__ x,
    float* __restrict__ out)
{
  __shared__ __align__(16) u16 As[128 * 32];
  __shared__ __align__(16) u16 Bs[128 * 32];
  const int tid = threadIdx.x;
  const int lane = tid & 63, wave = tid >> 6;
  const int wm = wave >> 1, wn = wave & 1;
  const int m0 = blockIdx.x * 128;
  const int n0g = blockIdx.y * 128;
  const int b = n0g >> 13, t0 = n0g & (T_ - 1);
  const int srow = tid >> 2;
  const int skk  = (tid & 3) * 8;

  f32x4 acc[4][4];
#pragma unroll
  for (int i = 0; i < 4; ++i)
#pragma unroll
    for (int j = 0; j < 4; ++j) acc[i][j] = (f32x4){0.f, 0.f, 0.f, 0.f};

  const int aoff = (wm * 64 + (lane & 15)) * 32 + (lane >> 4) * 8;
  const int boff = (wn * 64 + (lane & 15)) * 32 + (lane >> 4) * 8;
  const size_t ztb = (size_t)b * T_ * C_;

  for (int kc = 0; kc < 16; ++kc) {
    const int k = kc * 32 + skk;        // 0..511
    const u16* gA = W2 + (size_t)(m0 + srow) * 512 + k;
    const u16* gB = Zt + ztb + (size_t)(t0 + srow) * C_ + k;
    gload_lds16(gA,            As + tid * 8);
    gload_lds16(gA + 64 * 512, As + 2048 + tid * 8);
    gload_lds16(gB,            Bs + tid * 8);
    gload_lds16(gB + 64 * C_,  Bs + 2048 + tid * 8);
    asm volatile("s_waitcnt vmcnt(0)" ::: "memory");
    __syncthreads();
    bf16x8 af[4], bfr[4];
#pragma unroll
    for (int i = 0; i < 4; ++i) af[i]  = *(const bf16x8*)(As + aoff + i * 512);
#pragma unroll
    for (int j = 0; j < 4; ++j) bfr[j] = *(const bf16x8*)(Bs + boff + j * 512);
#pragma unroll
    for (int i = 0; i < 4; ++i)
#pragma unroll
      for (int j = 0; j < 4; ++j)
        acc[i][j] = __builtin_amdgcn_mfma_f32_16x16x32_bf16(af[i], bfr[j], acc[i][j], 0, 0, 0);
    __syncthreads();
  }

#pragma unroll
  for (int i = 0; i < 4; ++i) {
    const int R = m0 + wm * 64 + i * 16 + ((lane >> 4) << 2);
    const float b20 = b2[R], b21 = b2[R + 1], b22 = b2[R + 2], b23 = b2[R + 3];
#pragma unroll
    for (int j = 0; j < 4; ++j) {
      const int ttc = t0 + wn * 64 + j * 16 + (lane & 15);
      f32x4 v = acc[i][j];
      float vals[4] = {v[0] + b20, v[1] + b21, v[2] + b22, v[3] + b23};
#pragma unroll
      for (int jj = 0; jj < 4; ++jj) {
        int r = R + jj;
        if (r < 512) {
          size_t o = ((size_t)(b * 512 + r)) * T_ + ttc;
          out[o] = (x[o] + vals[jj]) * 0.70710678118654752f;
        } else {
          size_t o = (size_t)33554432 + ((size_t)(b * 256 + (r - 512))) * T_ + ttc;
          out[o] = vals[jj];
        }
      }
    }
  }
}

extern "C" void kernel_launch(void* const* d_in, const int* in_sizes, int n_in,
                              void* d_out, int out_size, void* d_ws, size_t ws_size,
                              hipStream_t stream) {
  const float* x  = (const float*)d_in[0];
  const float* fw = (const float*)d_in[1];
  const float* fb = (const float*)d_in[2];
  const float* gw = (const float*)d_in[3];
  const float* gb = (const float*)d_in[4];
  const float* rw = (const float*)d_in[5];
  const float* rb = (const float*)d_in[6];
  const float* sw = (const float*)d_in[7];
  const float* sb = (const float*)d_in[8];
  const int* dil  = (const int*)d_in[9];

  char* ws = (char*)d_ws;
  u16*   Wbig = (u16*)(ws + OFF_WBIG);
  u16*   W2   = (u16*)(ws + OFF_W2);
  float* b1   = (float*)(ws + OFF_B1);
  float* b2   = (float*)(ws + OFF_B2);
  u16*   Xt   = (u16*)(ws + OFF_XT);
  u16*   Zt   = (u16*)(ws + OFF_ZT);
  float* out  = (float*)d_out;

  hipLaunchKernelGGL(pack_kernel, dim3(5767), dim3(256), 0, stream,
                     fw, fb, gw, gb, rw, rb, sw, sb, Wbig, W2, b1, b2, Xt);
  hipLaunchKernelGGL(transpose_kernel, dim3(8192), dim3(256), 0, stream, x, Xt);
  hipLaunchKernelGGL(gemm1_kernel, dim3(8, 512), dim3(256), 0, stream, Wbig, Xt, b1, Zt, dil);
  hipLaunchKernelGGL(gemm2_kernel, dim3(6, 512), dim3(256), 0, stream, W2, Zt, b2, x, out);
}

// Round 2
// 404.930 us; speedup vs baseline: 1.0569x; 1.0569x over previous
//
#include <hip/hip_runtime.h>
#include <hip/hip_bf16.h>

typedef __attribute__((ext_vector_type(4))) float f32x4;
typedef __attribute__((ext_vector_type(8))) short bf16x8;
typedef unsigned int   u32;
typedef unsigned short u16;

#define DPAD 8
#define B_   8
#define C_   512
#define T_   8192
#define S_   256

// workspace byte offsets
#define OFF_WBIG 0u          // u16[1024*1024]      = 2,097,152 B
#define OFF_W2   2097152u    // u16[768*512]        =   786,432 B
#define OFF_B1   2883584u    // float[1024]
#define OFF_B2   2887680u    // float[768]
#define OFF_XT   2891776u    // u16[8*(8192+8)*512] = 67,174,400 B
#define OFF_ZT   70066176u   // u16[8*8192*512]     = 67,108,864 B

__device__ __forceinline__ u16 f2bf(float f) {
  u32 u = __builtin_bit_cast(u32, f);
  u += 0x7FFFu + ((u >> 16) & 1u);
  return (u16)(u >> 16);
}
__device__ __forceinline__ float sigm_(float x) { return 1.0f / (1.0f + __expf(-x)); }
__device__ __forceinline__ float tanh_(float x) { return 2.0f / (1.0f + __expf(-2.0f * x)) - 1.0f; }

__device__ __forceinline__ void gload_lds16(const void* g, void* l) {
  __builtin_amdgcn_global_load_lds(
      (const __attribute__((address_space(1))) void*)g,
      (__attribute__((address_space(3))) void*)l, 16, 0, 0);
}

// ---------------- pack weights / biases, zero Xt pad rows ----------------
__global__ void pack_kernel(const float* __restrict__ fw, const float* __restrict__ fb,
                            const float* __restrict__ gw, const float* __restrict__ gb,
                            const float* __restrict__ rw, const float* __restrict__ rb,
                            const float* __restrict__ sw, const float* __restrict__ sb,
                            u16* __restrict__ Wbig, u16* __restrict__ W2,
                            float* __restrict__ b1, float* __restrict__ b2,
                            u16* __restrict__ Xt)
{
  int idx = blockIdx.x * 256 + threadIdx.x;
  if (idx < 1048576) {                    // Wbig[row][k], row 2i=filter i, 2i+1=gate i
    int row = idx >> 10, k = idx & 1023;  // k<512: tap1 (x[t]); k>=512: tap0 (x[t-d])
    int i = row >> 1;
    const float* src = (row & 1) ? gw : fw;
    float v = src[((i << 9) + (k & 511)) * 2 + ((k < 512) ? 1 : 0)];
    Wbig[idx] = f2bf(v);
    return;
  }
  idx -= 1048576;
  if (idx < 393216) {                     // W2[r][k]: r<512 res, else skip
    int r = idx >> 9, k = idx & 511;
    float v = (r < 512) ? rw[(r << 9) + k] : sw[((r - 512) << 9) + k];
    W2[idx] = f2bf(v);
    return;
  }
  idx -= 393216;
  if (idx < 1024) { b1[idx] = (idx & 1) ? gb[idx >> 1] : fb[idx >> 1]; return; }
  idx -= 1024;
  if (idx < 768) { b2[idx] = (idx < 512) ? rb[idx] : sb[idx - 512]; return; }
  idx -= 768;
  if (idx < B_ * DPAD * C_) {             // zero causal pad rows of Xt
    int b = idx >> 12;                    // DPAD*C_ = 4096
    int rest = idx & 4095;
    Xt[(size_t)b * (T_ + DPAD) * C_ + rest] = 0;
  }
}

// ---------------- x [B][C][T] f32 -> Xt [B][DPAD+T][C] bf16 ----------------
__global__ __launch_bounds__(256) void transpose_kernel(const float* __restrict__ x,
                                                        u16* __restrict__ Xt)
{
  __shared__ float tile[64][65];
  int bid = blockIdx.x;
  int ct = bid & 7, tt = (bid >> 3) & 127, b = bid >> 10;
  int w = threadIdx.x >> 6, ln = threadIdx.x & 63;
  const float* xp = x + ((size_t)(b * C_ + ct * 64)) * T_ + tt * 64;
#pragma unroll
  for (int r = 0; r < 16; ++r) {
    int cl = r * 4 + w;
    tile[cl][ln] = xp[(size_t)cl * T_ + ln];
  }
  __syncthreads();
  u16* op = Xt + ((size_t)b * (T_ + DPAD) + DPAD + tt * 64) * C_ + ct * 64;
#pragma unroll
  for (int r = 0; r < 16; ++r) {
    int tl = r * 4 + w;
    op[(size_t)tl * C_ + ln] = f2bf(tile[ln][tl]);
  }
}

// ---------------- GEMM1: [1024x1024] x [1024 x 65536] + gated activation ----------------
// 1-D grid of 4096 blocks; XCD-aware swizzle: xcd = bid&7 owns n-chunk of 64
// n-tiles and iterates all 8 m-tiles back-to-back (m fastest) so the B-panel
// for a given n is fetched once into that XCD's L2 and reused by all m-tiles.
__global__ __launch_bounds__(256, 2) void gemm1_kernel(
    const u16* __restrict__ W, const u16* __restrict__ Xt,
    const float* __restrict__ b1, u16* __restrict__ Zt,
    const int* __restrict__ dptr)
{
  __shared__ __align__(16) u16 As[128 * 32];
  __shared__ __align__(16) u16 Bs[128 * 32];
  const int d = *dptr;
  const int tid = threadIdx.x;
  const int lane = tid & 63, wave = tid >> 6;
  const int wm = wave >> 1, wn = wave & 1;

  const int bid = blockIdx.x;
  const int xcd = bid & 7;
  const int idx = bid >> 3;            // 0..511 within XCD
  const int mt  = idx & 7;             // m-tile 0..7 (fastest -> B-panel reuse)
  const int nt  = (xcd << 6) | (idx >> 3);  // n-tile 0..511
  const int m0 = mt * 128;
  const int n0g = nt * 128;
  const int b = n0g >> 13, t0 = n0g & (T_ - 1);
  const int srow = tid >> 2;          // 0..63
  const int skk  = (tid & 3) * 8;     // 0,8,16,24

  f32x4 acc[4][4];
#pragma unroll
  for (int i = 0; i < 4; ++i)
#pragma unroll
    for (int j = 0; j < 4; ++j) acc[i][j] = (f32x4){0.f, 0.f, 0.f, 0.f};

  const int aoff = (wm * 64 + (lane & 15)) * 32 + (lane >> 4) * 8;
  const int boff = (wn * 64 + (lane & 15)) * 32 + (lane >> 4) * 8;
  const size_t xtb = (size_t)b * (T_ + DPAD) * C_;

  for (int kc = 0; kc < 32; ++kc) {
    const int k = kc * 32 + skk;        // 0..1023
    const int col = k & 511;
    const int rsh = (k >= 512) ? d : 0; // tap0 reads t-d rows (pad rows are zero)
    const u16* gA = W + (size_t)(m0 + srow) * 1024 + k;
    const u16* gB = Xt + xtb + (size_t)(DPAD + t0 + srow - rsh) * C_ + col;
    gload_lds16(gA,             As + tid * 8);
    gload_lds16(gA + 64 * 1024, As + 2048 + tid * 8);
    gload_lds16(gB,             Bs + tid * 8);
    gload_lds16(gB + 64 * C_,   Bs + 2048 + tid * 8);
    asm volatile("s_waitcnt vmcnt(0)" ::: "memory");
    __syncthreads();
    bf16x8 af[4], bfr[4];
#pragma unroll
    for (int i = 0; i < 4; ++i) af[i]  = *(const bf16x8*)(As + aoff + i * 512);
#pragma unroll
    for (int j = 0; j < 4; ++j) bfr[j] = *(const bf16x8*)(Bs + boff + j * 512);
#pragma unroll
    for (int i = 0; i < 4; ++i)
#pragma unroll
      for (int j = 0; j < 4; ++j)
        acc[i][j] = __builtin_amdgcn_mfma_f32_16x16x32_bf16(af[i], bfr[j], acc[i][j], 0, 0, 0);
    __syncthreads();
  }

  // epilogue: rows R..R+3 = (filter c0, gate c0, filter c0+1, gate c0+1)
#pragma unroll
  for (int i = 0; i < 4; ++i) {
    const int R = m0 + wm * 64 + i * 16 + ((lane >> 4) << 2);
    const float bi0 = b1[R], bi1 = b1[R + 1], bi2 = b1[R + 2], bi3 = b1[R + 3];
    const int c0 = R >> 1;
#pragma unroll
    for (int j = 0; j < 4; ++j) {
      const int ttc = t0 + wn * 64 + j * 16 + (lane & 15);
      f32x4 v = acc[i][j];
      float z0 = tanh_(v[0] + bi0) * sigm_(v[1] + bi1);
      float z1 = tanh_(v[2] + bi2) * sigm_(v[3] + bi3);
      u32 p = (u32)f2bf(z0) | ((u32)f2bf(z1) << 16);
      *(u32*)(Zt + (size_t)(b * T_ + ttc) * C_ + c0) = p;
    }
  }
}

// ---------------- GEMM2: [768x512] x z + residual/skip epilogue ----------------
// 3072 blocks; same XCD swizzle: 6 m-tiles fastest within each XCD's n-chunk.
__global__ __launch_bounds__(256, 2) void gemm2_kernel(
    const u16* __restrict__ W2, const u16* __restrict__ Zt,
    const float* __restrict__ b2, const float* __restrict__ x,
    float* __restrict__ out)
{
  __shared__ __align__(16) u16 As[128 * 32];
  __shared__ __align__(16) u16 Bs[128 * 32];
  const int tid = threadIdx.x;
  const int lane = tid & 63, wave = tid >> 6;
  const int wm = wave >> 1, wn = wave & 1;

  const int bid = blockIdx.x;
  const int xcd = bid & 7;
  const int idx = bid >> 3;            // 0..383
  const int mt  = idx % 6;
  const int nt  = (xcd << 6) + idx / 6;
  const int m0 = mt * 128;
  const int n0g = nt * 128;
  const int b = n0g >> 13, t0 = n0g & (T_ - 1);
  const int srow = tid >> 2;
  const int skk  = (tid & 3) * 8;

  f32x4 acc[4][4];
#pragma unroll
  for (int i = 0; i < 4; ++i)
#pragma unroll
    for (int j = 0; j < 4; ++j) acc[i][j] = (f32x4){0.f, 0.f, 0.f, 0.f};

  const int aoff = (wm * 64 + (lane & 15)) * 32 + (lane >> 4) * 8;
  const int boff = (wn * 64 + (lane & 15)) * 32 + (lane >> 4) * 8;
  const size_t ztb = (size_t)b * T_ * C_;

  for (int kc = 0; kc < 16; ++kc) {
    const int k = kc * 32 + skk;        // 0..511
    const u16* gA = W2 + (size_t)(m0 + srow) * 512 + k;
    const u16* gB = Zt + ztb + (size_t)(t0 + srow) * C_ + k;
    gload_lds16(gA,            As + tid * 8);
    gload_lds16(gA + 64 * 512, As + 2048 + tid * 8);
    gload_lds16(gB,            Bs + tid * 8);
    gload_lds16(gB + 64 * C_,  Bs + 2048 + tid * 8);
    asm volatile("s_waitcnt vmcnt(0)" ::: "memory");
    __syncthreads();
    bf16x8 af[4], bfr[4];
#pragma unroll
    for (int i = 0; i < 4; ++i) af[i]  = *(const bf16x8*)(As + aoff + i * 512);
#pragma unroll
    for (int j = 0; j < 4; ++j) bfr[j] = *(const bf16x8*)(Bs + boff + j * 512);
#pragma unroll
    for (int i = 0; i < 4; ++i)
#pragma unroll
      for (int j = 0; j < 4; ++j)
        acc[i][j] = __builtin_amdgcn_mfma_f32_16x16x32_bf16(af[i], bfr[j], acc[i][j], 0, 0, 0);
    __syncthreads();
  }

#pragma unroll
  for (int i = 0; i < 4; ++i) {
    const int R = m0 + wm * 64 + i * 16 + ((lane >> 4) << 2);
    const float b20 = b2[R], b21 = b2[R + 1], b22 = b2[R + 2], b23 = b2[R + 3];
#pragma unroll
    for (int j = 0; j < 4; ++j) {
      const int ttc = t0 + wn * 64 + j * 16 + (lane & 15);
      f32x4 v = acc[i][j];
      float vals[4] = {v[0] + b20, v[1] + b21, v[2] + b22, v[3] + b23};
#pragma unroll
      for (int jj = 0; jj < 4; ++jj) {
        int r = R + jj;
        if (r < 512) {
          size_t o = ((size_t)(b * 512 + r)) * T_ + ttc;
          out[o] = (x[o] + vals[jj]) * 0.70710678118654752f;
        } else {
          size_t o = (size_t)33554432 + ((size_t)(b * 256 + (r - 512))) * T_ + ttc;
          out[o] = vals[jj];
        }
      }
    }
  }
}

extern "C" void kernel_launch(void* const* d_in, const int* in_sizes, int n_in,
                              void* d_out, int out_size, void* d_ws, size_t ws_size,
                              hipStream_t stream) {
  const float* x  = (const float*)d_in[0];
  const float* fw = (const float*)d_in[1];
  const float* fb = (const float*)d_in[2];
  const float* gw = (const float*)d_in[3];
  const float* gb = (const float*)d_in[4];
  const float* rw = (const float*)d_in[5];
  const float* rb = (const float*)d_in[6];
  const float* sw = (const float*)d_in[7];
  const float* sb = (const float*)d_in[8];
  const int* dil  = (const int*)d_in[9];

  char* ws = (char*)d_ws;
  u16*   Wbig = (u16*)(ws + OFF_WBIG);
  u16*   W2   = (u16*)(ws + OFF_W2);
  float* b1   = (float*)(ws + OFF_B1);
  float* b2   = (float*)(ws + OFF_B2);
  u16*   Xt   = (u16*)(ws + OFF_XT);
  u16*   Zt   = (u16*)(ws + OFF_ZT);
  float* out  = (float*)d_out;

  hipLaunchKernelGGL(pack_kernel, dim3(5767), dim3(256), 0, stream,
                     fw, fb, gw, gb, rw, rb, sw, sb, Wbig, W2, b1, b2, Xt);
  hipLaunchKernelGGL(transpose_kernel, dim3(8192), dim3(256), 0, stream, x, Xt);
  hipLaunchKernelGGL(gemm1_kernel, dim3(4096), dim3(256), 0, stream, Wbig, Xt, b1, Zt, dil);
  hipLaunchKernelGGL(gemm2_kernel, dim3(3072), dim3(256), 0, stream, W2, Zt, b2, x, out);
}

// Round 4
// 334.823 us; speedup vs baseline: 1.2782x; 1.2094x over previous
//
#include <hip/hip_runtime.h>
#include <hip/hip_bf16.h>

typedef __attribute__((ext_vector_type(4))) float f32x4;
typedef __attribute__((ext_vector_type(8))) short bf16x8;
typedef unsigned int   u32;
typedef unsigned short u16;

#define DPAD 8
#define B_   8
#define C_   512
#define T_   8192
#define S_   256

// workspace byte offsets
#define OFF_WBIG 0u          // u16[1024*1024]      = 2,097,152 B
#define OFF_W2   2097152u    // u16[768*512]        =   786,432 B
#define OFF_B1   2883584u    // float[1024]
#define OFF_B2   2887680u    // float[768]
#define OFF_XT   2891776u    // u16[8*(8192+8)*512] = 67,174,400 B
#define OFF_ZT   70066176u   // u16[8*8192*512]     = 67,108,864 B

__device__ __forceinline__ u16 f2bf(float f) {
  u32 u = __builtin_bit_cast(u32, f);
  u += 0x7FFFu + ((u >> 16) & 1u);
  return (u16)(u >> 16);
}
__device__ __forceinline__ float sigm_(float x) { return 1.0f / (1.0f + __expf(-x)); }
__device__ __forceinline__ float tanh_(float x) { return 2.0f / (1.0f + __expf(-2.0f * x)) - 1.0f; }

__device__ __forceinline__ void gload_lds16(const void* g, void* l) {
  __builtin_amdgcn_global_load_lds(
      (const __attribute__((address_space(1))) void*)g,
      (__attribute__((address_space(3))) void*)l, 16, 0, 0);
}

// ---------------- pack weights / biases, zero Xt pad rows ----------------
__global__ void pack_kernel(const float* __restrict__ fw, const float* __restrict__ fb,
                            const float* __restrict__ gw, const float* __restrict__ gb,
                            const float* __restrict__ rw, const float* __restrict__ rb,
                            const float* __restrict__ sw, const float* __restrict__ sb,
                            u16* __restrict__ Wbig, u16* __restrict__ W2,
                            float* __restrict__ b1, float* __restrict__ b2,
                            u16* __restrict__ Xt)
{
  int idx = blockIdx.x * 256 + threadIdx.x;
  if (idx < 1048576) {                    // Wbig[row][k], row 2i=filter i, 2i+1=gate i
    int row = idx >> 10, k = idx & 1023;  // k<512: tap1 (x[t]); k>=512: tap0 (x[t-d])
    int i = row >> 1;
    const float* src = (row & 1) ? gw : fw;
    float v = src[((i << 9) + (k & 511)) * 2 + ((k < 512) ? 1 : 0)];
    Wbig[idx] = f2bf(v);
    return;
  }
  idx -= 1048576;
  if (idx < 393216) {                     // W2[r][k]: r<512 res, else skip
    int r = idx >> 9, k = idx & 511;
    float v = (r < 512) ? rw[(r << 9) + k] : sw[((r - 512) << 9) + k];
    W2[idx] = f2bf(v);
    return;
  }
  idx -= 393216;
  if (idx < 1024) { b1[idx] = (idx & 1) ? gb[idx >> 1] : fb[idx >> 1]; return; }
  idx -= 1024;
  if (idx < 768) { b2[idx] = (idx < 512) ? rb[idx] : sb[idx - 512]; return; }
  idx -= 768;
  if (idx < B_ * DPAD * C_) {             // zero causal pad rows of Xt
    int b = idx >> 12;                    // DPAD*C_ = 4096
    int rest = idx & 4095;
    Xt[(size_t)b * (T_ + DPAD) * C_ + rest] = 0;
  }
}

// ---------------- x [B][C][T] f32 -> Xt [B][DPAD+T][C] bf16 ----------------
__global__ __launch_bounds__(256) void transpose_kernel(const float* __restrict__ x,
                                                        u16* __restrict__ Xt)
{
  __shared__ float tile[64][65];
  int bid = blockIdx.x;
  int ct = bid & 7, tt = (bid >> 3) & 127, b = bid >> 10;
  int w = threadIdx.x >> 6, ln = threadIdx.x & 63;
  const float* xp = x + ((size_t)(b * C_ + ct * 64)) * T_ + tt * 64;
#pragma unroll
  for (int r = 0; r < 16; ++r) {
    int cl = r * 4 + w;
    tile[cl][ln] = xp[(size_t)cl * T_ + ln];
  }
  __syncthreads();
  u16* op = Xt + ((size_t)b * (T_ + DPAD) + DPAD + tt * 64) * C_ + ct * 64;
#pragma unroll
  for (int r = 0; r < 16; ++r) {
    int tl = r * 4 + w;
    op[(size_t)tl * C_ + ln] = f2bf(tile[ln][tl]);
  }
}

// ---------------- GEMM1: [1024x1024] x [1024 x 65536] + gated activation ----------------
__global__ __launch_bounds__(256, 2) void gemm1_kernel(
    const u16* __restrict__ W, const u16* __restrict__ Xt,
    const float* __restrict__ b1, u16* __restrict__ Zt,
    const int* __restrict__ dptr)
{
  __shared__ __align__(16) u16 As[128 * 32];
  __shared__ __align__(16) u16 Bs[128 * 32];
  const int d = *dptr;
  const int tid = threadIdx.x;
  const int lane = tid & 63, wave = tid >> 6;
  const int wm = wave >> 1, wn = wave & 1;

  const int bid = blockIdx.x;
  const int xcd = bid & 7;
  const int idx = bid >> 3;            // 0..511 within XCD
  const int mt  = idx & 7;             // m-tile 0..7 (fastest -> B-panel reuse)
  const int nt  = (xcd << 6) | (idx >> 3);  // n-tile 0..511
  const int m0 = mt * 128;
  const int n0g = nt * 128;
  const int b = n0g >> 13, t0 = n0g & (T_ - 1);
  const int srow = tid >> 2;          // 0..63
  const int skk  = (tid & 3) * 8;     // 0,8,16,24

  f32x4 acc[4][4];
#pragma unroll
  for (int i = 0; i < 4; ++i)
#pragma unroll
    for (int j = 0; j < 4; ++j) acc[i][j] = (f32x4){0.f, 0.f, 0.f, 0.f};

  const int aoff = (wm * 64 + (lane & 15)) * 32 + (lane >> 4) * 8;
  const int boff = (wn * 64 + (lane & 15)) * 32 + (lane >> 4) * 8;
  const size_t xtb = (size_t)b * (T_ + DPAD) * C_;

  for (int kc = 0; kc < 32; ++kc) {
    const int k = kc * 32 + skk;        // 0..1023
    const int col = k & 511;
    const int rsh = (k >= 512) ? d : 0; // tap0 reads t-d rows (pad rows are zero)
    const u16* gA = W + (size_t)(m0 + srow) * 1024 + k;
    const u16* gB = Xt + xtb + (size_t)(DPAD + t0 + srow - rsh) * C_ + col;
    gload_lds16(gA,             As + tid * 8);
    gload_lds16(gA + 64 * 1024, As + 2048 + tid * 8);
    gload_lds16(gB,             Bs + tid * 8);
    gload_lds16(gB + 64 * C_,   Bs + 2048 + tid * 8);
    asm volatile("s_waitcnt vmcnt(0)" ::: "memory");
    __syncthreads();
    bf16x8 af[4], bfr[4];
#pragma unroll
    for (int i = 0; i < 4; ++i) af[i]  = *(const bf16x8*)(As + aoff + i * 512);
#pragma unroll
    for (int j = 0; j < 4; ++j) bfr[j] = *(const bf16x8*)(Bs + boff + j * 512);
#pragma unroll
    for (int i = 0; i < 4; ++i)
#pragma unroll
      for (int j = 0; j < 4; ++j)
        acc[i][j] = __builtin_amdgcn_mfma_f32_16x16x32_bf16(af[i], bfr[j], acc[i][j], 0, 0, 0);
    __syncthreads();
  }

  // epilogue: rows R..R+3 = (filter c0, gate c0, filter c0+1, gate c0+1)
#pragma unroll
  for (int i = 0; i < 4; ++i) {
    const int R = m0 + wm * 64 + i * 16 + ((lane >> 4) << 2);
    const float bi0 = b1[R], bi1 = b1[R + 1], bi2 = b1[R + 2], bi3 = b1[R + 3];
    const int c0 = R >> 1;
#pragma unroll
    for (int j = 0; j < 4; ++j) {
      const int ttc = t0 + wn * 64 + j * 16 + (lane & 15);
      f32x4 v = acc[i][j];
      float z0 = tanh_(v[0] + bi0) * sigm_(v[1] + bi1);
      float z1 = tanh_(v[2] + bi2) * sigm_(v[3] + bi3);
      u32 p = (u32)f2bf(z0) | ((u32)f2bf(z1) << 16);
      *(u32*)(Zt + (size_t)(b * T_ + ttc) * C_ + c0) = p;
    }
  }
}

// ---------------- GEMM2: [768x512] x z + residual/skip epilogue ----------------
// k-loop: proven round-2 structure (vmcnt(0) drain + __syncthreads, single buffer).
// Epilogue: per-wave LDS transpose in a DISJOINT, wave-private region -> f32x4
// coalesced x-loads / out-stores along t. No barrier needed around it.
__global__ __launch_bounds__(256, 4) void gemm2_kernel(
    const u16* __restrict__ W2, const u16* __restrict__ Zt,
    const float* __restrict__ b2, const float* __restrict__ x,
    float* __restrict__ out)
{
  __shared__ __align__(16) u16 As[128 * 32];
  __shared__ __align__(16) u16 Bs[128 * 32];
  __shared__ __align__(16) float fstall[4 * 1088];   // 4 waves x 16x68 padded
  const int tid = threadIdx.x;
  const int lane = tid & 63, wave = tid >> 6;
  const int wm = wave >> 1, wn = wave & 1;

  const int bid = blockIdx.x;
  const int xcd = bid & 7;
  const int idx = bid >> 3;            // 0..383
  const int mt  = idx % 6;
  const int nt  = (xcd << 6) + idx / 6;
  const int m0 = mt * 128;
  const int n0g = nt * 128;
  const int b = n0g >> 13, t0 = n0g & (T_ - 1);
  const int srow = tid >> 2;
  const int skk  = (tid & 3) * 8;

  f32x4 acc[4][4];
#pragma unroll
  for (int i = 0; i < 4; ++i)
#pragma unroll
    for (int j = 0; j < 4; ++j) acc[i][j] = (f32x4){0.f, 0.f, 0.f, 0.f};

  const int aoff = (wm * 64 + (lane & 15)) * 32 + (lane >> 4) * 8;
  const int boff = (wn * 64 + (lane & 15)) * 32 + (lane >> 4) * 8;
  const size_t ztb = (size_t)b * T_ * C_;

  for (int kc = 0; kc < 16; ++kc) {
    const int k = kc * 32 + skk;        // 0..511
    const u16* gA = W2 + (size_t)(m0 + srow) * 512 + k;
    const u16* gB = Zt + ztb + (size_t)(t0 + srow) * C_ + k;
    gload_lds16(gA,            As + tid * 8);
    gload_lds16(gA + 64 * 512, As + 2048 + tid * 8);
    gload_lds16(gB,            Bs + tid * 8);
    gload_lds16(gB + 64 * C_,  Bs + 2048 + tid * 8);
    asm volatile("s_waitcnt vmcnt(0)" ::: "memory");
    __syncthreads();
    bf16x8 af[4], bfr[4];
#pragma unroll
    for (int i = 0; i < 4; ++i) af[i]  = *(const bf16x8*)(As + aoff + i * 512);
#pragma unroll
    for (int j = 0; j < 4; ++j) bfr[j] = *(const bf16x8*)(Bs + boff + j * 512);
#pragma unroll
    for (int i = 0; i < 4; ++i)
#pragma unroll
      for (int j = 0; j < 4; ++j)
        acc[i][j] = __builtin_amdgcn_mfma_f32_16x16x32_bf16(af[i], bfr[j], acc[i][j], 0, 0, 0);
    __syncthreads();
  }

  // ---- coalesced epilogue: per-wave private LDS transpose of 16x64 quadrants ----
  float* const fst = fstall + wave * 1088;         // 16 rows x 68 (padded)
  const int g = lane >> 4, p = lane & 15;
  const bool isres = (m0 < 512);

#pragma unroll
  for (int i = 0; i < 4; ++i) {
    // write quadrant i: row (g*4+r) of 16, col j*16+p of 64
#pragma unroll
    for (int j = 0; j < 4; ++j)
#pragma unroll
      for (int r = 0; r < 4; ++r)
        fst[(g * 4 + r) * 68 + j * 16 + p] = acc[i][j][r];
    // read back along t and store coalesced (wave-private region, same-wave
    // DS ops are in-order; compiler inserts lgkmcnt waits)
#pragma unroll
    for (int q = 0; q < 4; ++q) {
      const int lrow = q * 4 + g;                  // 0..15
      const int row = m0 + wm * 64 + i * 16 + lrow;
      const int t = t0 + wn * 64 + p * 4;
      f32x4 v = *(const f32x4*)&fst[lrow * 68 + p * 4];
      const float bias = b2[row];
      f32x4 res;
      if (isres) {
        const size_t o = ((size_t)(b * 512 + row)) * T_ + t;
        f32x4 xv = *(const f32x4*)(x + o);
#pragma unroll
        for (int e = 0; e < 4; ++e)
          res[e] = (xv[e] + v[e] + bias) * 0.70710678118654752f;
        *(f32x4*)(out + o) = res;
      } else {
        const size_t o = (size_t)33554432 + ((size_t)(b * 256 + (row - 512))) * T_ + t;
#pragma unroll
        for (int e = 0; e < 4; ++e)
          res[e] = v[e] + bias;
        *(f32x4*)(out + o) = res;
      }
    }
  }
}

extern "C" void kernel_launch(void* const* d_in, const int* in_sizes, int n_in,
                              void* d_out, int out_size, void* d_ws, size_t ws_size,
                              hipStream_t stream) {
  const float* x  = (const float*)d_in[0];
  const float* fw = (const float*)d_in[1];
  const float* fb = (const float*)d_in[2];
  const float* gw = (const float*)d_in[3];
  const float* gb = (const float*)d_in[4];
  const float* rw = (const float*)d_in[5];
  const float* rb = (const float*)d_in[6];
  const float* sw = (const float*)d_in[7];
  const float* sb = (const float*)d_in[8];
  const int* dil  = (const int*)d_in[9];

  char* ws = (char*)d_ws;
  u16*   Wbig = (u16*)(ws + OFF_WBIG);
  u16*   W2   = (u16*)(ws + OFF_W2);
  float* b1   = (float*)(ws + OFF_B1);
  float* b2   = (float*)(ws + OFF_B2);
  u16*   Xt   = (u16*)(ws + OFF_XT);
  u16*   Zt   = (u16*)(ws + OFF_ZT);
  float* out  = (float*)d_out;

  hipLaunchKernelGGL(pack_kernel, dim3(5767), dim3(256), 0, stream,
                     fw, fb, gw, gb, rw, rb, sw, sb, Wbig, W2, b1, b2, Xt);
  hipLaunchKernelGGL(transpose_kernel, dim3(8192), dim3(256), 0, stream, x, Xt);
  hipLaunchKernelGGL(gemm1_kernel, dim3(4096), dim3(256), 0, stream, Wbig, Xt, b1, Zt, dil);
  hipLaunchKernelGGL(gemm2_kernel, dim3(3072), dim3(256), 0, stream, W2, Zt, b2, x, out);
}

// Round 5
// 317.286 us; speedup vs baseline: 1.3488x; 1.0553x over previous
//
#include <hip/hip_runtime.h>
#include <hip/hip_bf16.h>

typedef __attribute__((ext_vector_type(4))) float f32x4;
typedef __attribute__((ext_vector_type(8))) short bf16x8;
typedef unsigned int   u32;
typedef unsigned short u16;

#define DPAD 8
#define B_   8
#define C_   512
#define T_   8192
#define S_   256

// workspace byte offsets
#define OFF_WBIG 0u          // u16[1024*1024]      = 2,097,152 B
#define OFF_W2   2097152u    // u16[768*512]        =   786,432 B
#define OFF_B1   2883584u    // float[1024]
#define OFF_B2   2887680u    // float[768]
#define OFF_XT   2891776u    // u16[8*(8192+8)*512] = 67,174,400 B
#define OFF_ZT   70066176u   // u16[8*8192*512]     = 67,108,864 B

__device__ __forceinline__ u16 f2bf(float f) {
  u32 u = __builtin_bit_cast(u32, f);
  u += 0x7FFFu + ((u >> 16) & 1u);
  return (u16)(u >> 16);
}
__device__ __forceinline__ float sigm_(float x) { return 1.0f / (1.0f + __expf(-x)); }
__device__ __forceinline__ float tanh_(float x) { return 2.0f / (1.0f + __expf(-2.0f * x)) - 1.0f; }

__device__ __forceinline__ void gload_lds16(const void* g, void* l) {
  __builtin_amdgcn_global_load_lds(
      (const __attribute__((address_space(1))) void*)g,
      (__attribute__((address_space(3))) void*)l, 16, 0, 0);
}

// ---------------- pack weights / biases, zero Xt pad rows ----------------
__global__ void pack_kernel(const float* __restrict__ fw, const float* __restrict__ fb,
                            const float* __restrict__ gw, const float* __restrict__ gb,
                            const float* __restrict__ rw, const float* __restrict__ rb,
                            const float* __restrict__ sw, const float* __restrict__ sb,
                            u16* __restrict__ Wbig, u16* __restrict__ W2,
                            float* __restrict__ b1, float* __restrict__ b2,
                            u16* __restrict__ Xt)
{
  int idx = blockIdx.x * 256 + threadIdx.x;
  if (idx < 1048576) {                    // Wbig[row][k], row 2i=filter i, 2i+1=gate i
    int row = idx >> 10, k = idx & 1023;  // k<512: tap1 (x[t]); k>=512: tap0 (x[t-d])
    int i = row >> 1;
    const float* src = (row & 1) ? gw : fw;
    float v = src[((i << 9) + (k & 511)) * 2 + ((k < 512) ? 1 : 0)];
    Wbig[idx] = f2bf(v);
    return;
  }
  idx -= 1048576;
  if (idx < 393216) {                     // W2[r][k]: r<512 res, else skip
    int r = idx >> 9, k = idx & 511;
    float v = (r < 512) ? rw[(r << 9) + k] : sw[((r - 512) << 9) + k];
    W2[idx] = f2bf(v);
    return;
  }
  idx -= 393216;
  if (idx < 1024) { b1[idx] = (idx & 1) ? gb[idx >> 1] : fb[idx >> 1]; return; }
  idx -= 1024;
  if (idx < 768) { b2[idx] = (idx < 512) ? rb[idx] : sb[idx - 512]; return; }
  idx -= 768;
  if (idx < B_ * DPAD * C_) {             // zero causal pad rows of Xt
    int b = idx >> 12;                    // DPAD*C_ = 4096
    int rest = idx & 4095;
    Xt[(size_t)b * (T_ + DPAD) * C_ + rest] = 0;
  }
}

// ---------------- x [B][C][T] f32 -> Xt [B][DPAD+T][C] bf16 ----------------
__global__ __launch_bounds__(256) void transpose_kernel(const float* __restrict__ x,
                                                        u16* __restrict__ Xt)
{
  __shared__ float tile[64][65];
  int bid = blockIdx.x;
  int ct = bid & 7, tt = (bid >> 3) & 127, b = bid >> 10;
  int w = threadIdx.x >> 6, ln = threadIdx.x & 63;
  const float* xp = x + ((size_t)(b * C_ + ct * 64)) * T_ + tt * 64;
#pragma unroll
  for (int r = 0; r < 16; ++r) {
    int cl = r * 4 + w;
    tile[cl][ln] = xp[(size_t)cl * T_ + ln];
  }
  __syncthreads();
  u16* op = Xt + ((size_t)b * (T_ + DPAD) + DPAD + tt * 64) * C_ + ct * 64;
#pragma unroll
  for (int r = 0; r < 16; ++r) {
    int tl = r * 4 + w;
    op[(size_t)tl * C_ + ln] = f2bf(tile[ln][tl]);
  }
}

// ---------------- GEMM1: 256x256 tile, BK=64, 8 waves, deep pipeline ----------------
// Counted-vmcnt double-buffer: loads never drain to 0 inside the loop.
// LDS XOR-swizzle (16B-block ^= row&7) applied on the GLOBAL source at staging
// and on the ds_read address (both-sides; linear gload_lds dest).
__global__ __launch_bounds__(512, 2) void gemm1_kernel(
    const u16* __restrict__ W, const u16* __restrict__ Xt,
    const float* __restrict__ b1, u16* __restrict__ Zt,
    const int* __restrict__ dptr)
{
  __shared__ __align__(16) u16 smem[4 * 16384];   // 128 KB: A0 A1 B0 B1
  const int dcap = *dptr;
  const int tid = threadIdx.x;
  const int lane = tid & 63, wave = tid >> 6;
  const int wm = wave >> 2, wn = wave & 3;        // 2 x 4 waves -> 128x64 per wave

  const int bid = blockIdx.x;
  const int xcd = bid & 7;
  const int idx = bid >> 3;                 // 0..127 within XCD
  const int mt  = idx & 3;                  // m fastest -> B-panel L2 reuse
  const int nt  = (xcd << 5) | (idx >> 2);  // n-tile 0..255
  const int m0  = mt * 256;
  const int n0g = nt * 256;
  const int b = n0g >> 13, t0 = n0g & (T_ - 1);

  const int row0 = tid >> 3;                      // 0..63 (stage row base)
  const int ksw  = (((tid & 7) ^ (row0 & 7)) << 3); // swizzled k within tile
  const size_t xtb = (size_t)b * (T_ + DPAD) * C_;

  f32x4 acc[8][4];
#pragma unroll
  for (int i = 0; i < 8; ++i)
#pragma unroll
    for (int j = 0; j < 4; ++j) acc[i][j] = (f32x4){0.f, 0.f, 0.f, 0.f};

#define STAGE1(kt_, dd) do {                                                   \
    const int kglob_ = (kt_) * 64 + ksw;                                       \
    const int col_ = kglob_ & 511;                                             \
    const int rsh_ = (kglob_ >= 512) ? dcap : 0;                               \
    const u16* gA_ = W + (size_t)(m0 + row0) * 1024 + kglob_;                  \
    const u16* gB_ = Xt + xtb + (size_t)(DPAD + t0 + row0 - rsh_) * C_ + col_; \
    u16* As_ = smem + (dd) * 16384;                                            \
    u16* Bs_ = smem + 32768 + (dd) * 16384;                                    \
    _Pragma("unroll") for (int r_ = 0; r_ < 4; ++r_) {                         \
      gload_lds16(gA_ + (size_t)r_ * 64 * 1024, As_ + r_ * 4096 + tid * 8);    \
      gload_lds16(gB_ + (size_t)r_ * 64 * C_,   Bs_ + r_ * 4096 + tid * 8);    \
    }                                                                          \
  } while (0)

#define COMPUTE1(dd) do {                                                      \
    const u16* Ab_ = smem + (dd) * 16384;                                      \
    const u16* Bb_ = smem + 32768 + (dd) * 16384;                              \
    _Pragma("unroll") for (int s_ = 0; s_ < 2; ++s_) {                         \
      const int blk_ = ((s_ * 4 + (lane >> 4)) ^ (lane & 7)) * 8;              \
      bf16x8 af_[8], bf_[4];                                                   \
      _Pragma("unroll") for (int i_ = 0; i_ < 8; ++i_)                         \
        af_[i_] = *(const bf16x8*)(Ab_ + (wm * 128 + i_ * 16 + (lane & 15)) * 64 + blk_); \
      _Pragma("unroll") for (int j_ = 0; j_ < 4; ++j_)                         \
        bf_[j_] = *(const bf16x8*)(Bb_ + (wn * 64 + j_ * 16 + (lane & 15)) * 64 + blk_);  \
      __builtin_amdgcn_s_setprio(1);                                           \
      _Pragma("unroll") for (int i_ = 0; i_ < 8; ++i_)                         \
        _Pragma("unroll") for (int j_ = 0; j_ < 4; ++j_)                       \
          acc[i_][j_] = __builtin_amdgcn_mfma_f32_16x16x32_bf16(af_[i_], bf_[j_], acc[i_][j_], 0, 0, 0); \
      __builtin_amdgcn_s_setprio(0);                                           \
    }                                                                          \
  } while (0)

  STAGE1(0, 0);
  STAGE1(1, 1);
  for (int it = 0; it < 15; ++it) {
    asm volatile("s_waitcnt vmcnt(8)" ::: "memory");   // tile `it` landed; tile it+1 in flight
    __builtin_amdgcn_sched_barrier(0);
    __builtin_amdgcn_s_barrier();
    __builtin_amdgcn_sched_barrier(0);
    COMPUTE1(it & 1);
    __builtin_amdgcn_sched_barrier(0);
    __builtin_amdgcn_s_barrier();                      // all waves done reading buf
    __builtin_amdgcn_sched_barrier(0);
    if (it < 14) STAGE1(it + 2, it & 1);               // refill just-freed buffer
  }
  asm volatile("s_waitcnt vmcnt(0)" ::: "memory");
  __builtin_amdgcn_sched_barrier(0);
  __builtin_amdgcn_s_barrier();
  __builtin_amdgcn_sched_barrier(0);
  COMPUTE1(1);                                         // tile 15

  // epilogue: rows R..R+3 = (filter c0, gate c0, filter c0+1, gate c0+1)
  const int g = lane >> 4, p = lane & 15;
#pragma unroll
  for (int i = 0; i < 8; ++i) {
    const int R = m0 + wm * 128 + i * 16 + (g << 2);
    const float bi0 = b1[R], bi1 = b1[R + 1], bi2 = b1[R + 2], bi3 = b1[R + 3];
    const int c0 = R >> 1;
#pragma unroll
    for (int j = 0; j < 4; ++j) {
      const int ttc = t0 + wn * 64 + j * 16 + p;
      f32x4 v = acc[i][j];
      float z0 = tanh_(v[0] + bi0) * sigm_(v[1] + bi1);
      float z1 = tanh_(v[2] + bi2) * sigm_(v[3] + bi3);
      u32 pk = (u32)f2bf(z0) | ((u32)f2bf(z1) << 16);
      *(u32*)(Zt + (size_t)(b * T_ + ttc) * C_ + c0) = pk;
    }
  }
#undef STAGE1
#undef COMPUTE1
}

// ---------------- GEMM2: [768x512] x z + residual/skip epilogue ----------------
// k-loop: proven drain structure. Epilogue: per-wave LDS transpose in disjoint
// region -> f32x4 coalesced x-loads / out-stores along t.
__global__ __launch_bounds__(256, 4) void gemm2_kernel(
    const u16* __restrict__ W2, const u16* __restrict__ Zt,
    const float* __restrict__ b2, const float* __restrict__ x,
    float* __restrict__ out)
{
  __shared__ __align__(16) u16 As[128 * 32];
  __shared__ __align__(16) u16 Bs[128 * 32];
  __shared__ __align__(16) float fstall[4 * 1088];   // 4 waves x 16x68 padded
  const int tid = threadIdx.x;
  const int lane = tid & 63, wave = tid >> 6;
  const int wm = wave >> 1, wn = wave & 1;

  const int bid = blockIdx.x;
  const int xcd = bid & 7;
  const int idx = bid >> 3;            // 0..383
  const int mt  = idx % 6;
  const int nt  = (xcd << 6) + idx / 6;
  const int m0 = mt * 128;
  const int n0g = nt * 128;
  const int b = n0g >> 13, t0 = n0g & (T_ - 1);
  const int srow = tid >> 2;
  const int skk  = (tid & 3) * 8;

  f32x4 acc[4][4];
#pragma unroll
  for (int i = 0; i < 4; ++i)
#pragma unroll
    for (int j = 0; j < 4; ++j) acc[i][j] = (f32x4){0.f, 0.f, 0.f, 0.f};

  const int aoff = (wm * 64 + (lane & 15)) * 32 + (lane >> 4) * 8;
  const int boff = (wn * 64 + (lane & 15)) * 32 + (lane >> 4) * 8;
  const size_t ztb = (size_t)b * T_ * C_;

  for (int kc = 0; kc < 16; ++kc) {
    const int k = kc * 32 + skk;        // 0..511
    const u16* gA = W2 + (size_t)(m0 + srow) * 512 + k;
    const u16* gB = Zt + ztb + (size_t)(t0 + srow) * C_ + k;
    gload_lds16(gA,            As + tid * 8);
    gload_lds16(gA + 64 * 512, As + 2048 + tid * 8);
    gload_lds16(gB,            Bs + tid * 8);
    gload_lds16(gB + 64 * C_,  Bs + 2048 + tid * 8);
    asm volatile("s_waitcnt vmcnt(0)" ::: "memory");
    __syncthreads();
    bf16x8 af[4], bfr[4];
#pragma unroll
    for (int i = 0; i < 4; ++i) af[i]  = *(const bf16x8*)(As + aoff + i * 512);
#pragma unroll
    for (int j = 0; j < 4; ++j) bfr[j] = *(const bf16x8*)(Bs + boff + j * 512);
#pragma unroll
    for (int i = 0; i < 4; ++i)
#pragma unroll
      for (int j = 0; j < 4; ++j)
        acc[i][j] = __builtin_amdgcn_mfma_f32_16x16x32_bf16(af[i], bfr[j], acc[i][j], 0, 0, 0);
    __syncthreads();
  }

  // ---- coalesced epilogue: per-wave private LDS transpose of 16x64 quadrants ----
  float* const fst = fstall + wave * 1088;         // 16 rows x 68 (padded)
  const int g = lane >> 4, p = lane & 15;
  const bool isres = (m0 < 512);

#pragma unroll
  for (int i = 0; i < 4; ++i) {
#pragma unroll
    for (int j = 0; j < 4; ++j)
#pragma unroll
      for (int r = 0; r < 4; ++r)
        fst[(g * 4 + r) * 68 + j * 16 + p] = acc[i][j][r];
#pragma unroll
    for (int q = 0; q < 4; ++q) {
      const int lrow = q * 4 + g;                  // 0..15
      const int row = m0 + wm * 64 + i * 16 + lrow;
      const int t = t0 + wn * 64 + p * 4;
      f32x4 v = *(const f32x4*)&fst[lrow * 68 + p * 4];
      const float bias = b2[row];
      f32x4 res;
      if (isres) {
        const size_t o = ((size_t)(b * 512 + row)) * T_ + t;
        f32x4 xv = *(const f32x4*)(x + o);
#pragma unroll
        for (int e = 0; e < 4; ++e)
          res[e] = (xv[e] + v[e] + bias) * 0.70710678118654752f;
        *(f32x4*)(out + o) = res;
      } else {
        const size_t o = (size_t)33554432 + ((size_t)(b * 256 + (row - 512))) * T_ + t;
#pragma unroll
        for (int e = 0; e < 4; ++e)
          res[e] = v[e] + bias;
        *(f32x4*)(out + o) = res;
      }
    }
  }
}

extern "C" void kernel_launch(void* const* d_in, const int* in_sizes, int n_in,
                              void* d_out, int out_size, void* d_ws, size_t ws_size,
                              hipStream_t stream) {
  const float* x  = (const float*)d_in[0];
  const float* fw = (const float*)d_in[1];
  const float* fb = (const float*)d_in[2];
  const float* gw = (const float*)d_in[3];
  const float* gb = (const float*)d_in[4];
  const float* rw = (const float*)d_in[5];
  const float* rb = (const float*)d_in[6];
  const float* sw = (const float*)d_in[7];
  const float* sb = (const float*)d_in[8];
  const int* dil  = (const int*)d_in[9];

  char* ws = (char*)d_ws;
  u16*   Wbig = (u16*)(ws + OFF_WBIG);
  u16*   W2   = (u16*)(ws + OFF_W2);
  float* b1   = (float*)(ws + OFF_B1);
  float* b2   = (float*)(ws + OFF_B2);
  u16*   Xt   = (u16*)(ws + OFF_XT);
  u16*   Zt   = (u16*)(ws + OFF_ZT);
  float* out  = (float*)d_out;

  hipLaunchKernelGGL(pack_kernel, dim3(5767), dim3(256), 0, stream,
                     fw, fb, gw, gb, rw, rb, sw, sb, Wbig, W2, b1, b2, Xt);
  hipLaunchKernelGGL(transpose_kernel, dim3(8192), dim3(256), 0, stream, x, Xt);
  hipLaunchKernelGGL(gemm1_kernel, dim3(1024), dim3(512), 0, stream, Wbig, Xt, b1, Zt, dil);
  hipLaunchKernelGGL(gemm2_kernel, dim3(3072), dim3(256), 0, stream, W2, Zt, b2, x, out);
}

// Round 6
// 307.374 us; speedup vs baseline: 1.3923x; 1.0322x over previous
//
#include <hip/hip_runtime.h>
#include <hip/hip_bf16.h>

typedef __attribute__((ext_vector_type(4))) float f32x4;
typedef __attribute__((ext_vector_type(8))) short bf16x8;
typedef unsigned int   u32;
typedef unsigned short u16;

#define DPAD 8
#define B_   8
#define C_   512
#define T_   8192
#define S_   256

// workspace byte offsets
#define OFF_WBIG 0u          // u16[1024*1024]      = 2,097,152 B
#define OFF_W2   2097152u    // u16[768*512]        =   786,432 B
#define OFF_B1   2883584u    // float[1024]
#define OFF_B2   2887680u    // float[768]
#define OFF_XT   2891776u    // u16[8*(8192+8)*512] = 67,174,400 B
#define OFF_ZT   70066176u   // u16[8*8192*512]     = 67,108,864 B

__device__ __forceinline__ u16 f2bf(float f) {
  u32 u = __builtin_bit_cast(u32, f);
  u += 0x7FFFu + ((u >> 16) & 1u);
  return (u16)(u >> 16);
}
__device__ __forceinline__ float sigm_(float x) { return 1.0f / (1.0f + __expf(-x)); }
__device__ __forceinline__ float tanh_(float x) { return 2.0f / (1.0f + __expf(-2.0f * x)) - 1.0f; }

__device__ __forceinline__ void gload_lds16(const void* g, void* l) {
  __builtin_amdgcn_global_load_lds(
      (const __attribute__((address_space(1))) void*)g,
      (__attribute__((address_space(3))) void*)l, 16, 0, 0);
}

// ---------------- pack weights / biases, zero Xt pad rows ----------------
__global__ void pack_kernel(const float* __restrict__ fw, const float* __restrict__ fb,
                            const float* __restrict__ gw, const float* __restrict__ gb,
                            const float* __restrict__ rw, const float* __restrict__ rb,
                            const float* __restrict__ sw, const float* __restrict__ sb,
                            u16* __restrict__ Wbig, u16* __restrict__ W2,
                            float* __restrict__ b1, float* __restrict__ b2,
                            u16* __restrict__ Xt)
{
  int idx = blockIdx.x * 256 + threadIdx.x;
  if (idx < 1048576) {                    // Wbig[row][k], row 2i=filter i, 2i+1=gate i
    int row = idx >> 10, k = idx & 1023;  // k<512: tap1 (x[t]); k>=512: tap0 (x[t-d])
    int i = row >> 1;
    const float* src = (row & 1) ? gw : fw;
    float v = src[((i << 9) + (k & 511)) * 2 + ((k < 512) ? 1 : 0)];
    Wbig[idx] = f2bf(v);
    return;
  }
  idx -= 1048576;
  if (idx < 393216) {                     // W2[r][k]: r<512 res, else skip
    int r = idx >> 9, k = idx & 511;
    float v = (r < 512) ? rw[(r << 9) + k] : sw[((r - 512) << 9) + k];
    W2[idx] = f2bf(v);
    return;
  }
  idx -= 393216;
  if (idx < 1024) { b1[idx] = (idx & 1) ? gb[idx >> 1] : fb[idx >> 1]; return; }
  idx -= 1024;
  if (idx < 768) { b2[idx] = (idx < 512) ? rb[idx] : sb[idx - 512]; return; }
  idx -= 768;
  if (idx < B_ * DPAD * C_) {             // zero causal pad rows of Xt
    int b = idx >> 12;                    // DPAD*C_ = 4096
    int rest = idx & 4095;
    Xt[(size_t)b * (T_ + DPAD) * C_ + rest] = 0;
  }
}

// ---------------- x [B][C][T] f32 -> Xt [B][DPAD+T][C] bf16 ----------------
__global__ __launch_bounds__(256) void transpose_kernel(const float* __restrict__ x,
                                                        u16* __restrict__ Xt)
{
  __shared__ float tile[64][65];
  int bid = blockIdx.x;
  int ct = bid & 7, tt = (bid >> 3) & 127, b = bid >> 10;
  int w = threadIdx.x >> 6, ln = threadIdx.x & 63;
  const float* xp = x + ((size_t)(b * C_ + ct * 64)) * T_ + tt * 64;
#pragma unroll
  for (int r = 0; r < 16; ++r) {
    int cl = r * 4 + w;
    tile[cl][ln] = xp[(size_t)cl * T_ + ln];
  }
  __syncthreads();
  u16* op = Xt + ((size_t)b * (T_ + DPAD) + DPAD + tt * 64) * C_ + ct * 64;
#pragma unroll
  for (int r = 0; r < 16; ++r) {
    int tl = r * 4 + w;
    op[(size_t)tl * C_ + ln] = f2bf(tile[ln][tl]);
  }
}

// ---------------- GEMM1: 256x256, BK=64, 8 waves, 4 fine phases per K-tile ----------
// Per phase: [vmcnt if due] -> barrier -> ds_read frag subtile -> issue 2
// quarter-stages for tile t+1 -> setprio(1) -> 16 MFMA -> setprio(0).
// Stage order per tile: Bq0,Bq1 | Bq2,Bq3 | Aq0,Aq2 | Aq1,Aq3  (1 gload/thread each)
// Waits: phase0 vmcnt(2)  (Aq1,Aq3 of current tile still in flight)
//        phase2 vmcnt(4)  (next tile's 4 B quarters in flight)  -- never 0 in-loop.
// LDS rows 128B, 16B-slot ^= (row&7) swizzle on global src + ds_read (both sides).
__global__ __launch_bounds__(512, 2) void gemm1_kernel(
    const u16* __restrict__ W, const u16* __restrict__ Xt,
    const float* __restrict__ b1, u16* __restrict__ Zt,
    const int* __restrict__ dptr)
{
  __shared__ __align__(16) u16 smem[65536];   // 128 KB: A0 A1 B0 B1 (32 KB each)
  const int dcap = *dptr;
  const int tid = threadIdx.x;
  const int lane = tid & 63, wave = tid >> 6;
  const int wm = wave >> 2, wn = wave & 3;    // 2 x 4 waves -> 128x64 per wave
  const int lp = lane & 15, lg = lane >> 4, lx = lane & 7;

  const int bid = blockIdx.x;
  const int xcd = bid & 7;
  const int idx = bid >> 3;                 // 0..127 within XCD
  const int mt  = idx & 3;                  // m fastest -> B-panel L2 reuse
  const int nt  = (xcd << 5) | (idx >> 2);  // n-tile 0..255
  const int m0  = mt * 256;
  const int n0g = nt * 256;
  const int b = n0g >> 13, t0 = n0g & (T_ - 1);
  const size_t xtb = (size_t)b * (T_ + DPAD) * C_;

  const int srl = tid >> 3;                 // stage row-in-quarter 0..63
  const int skb = tid & 7;                  // stage 16B-block 0..7
  const int sxk = (skb ^ (srl & 7)) << 3;   // swizzled k-elem offset 0..56

  f32x4 acc[8][4];
#pragma unroll
  for (int i = 0; i < 8; ++i)
#pragma unroll
    for (int j = 0; j < 4; ++j) acc[i][j] = (f32x4){0.f, 0.f, 0.f, 0.f};

#define SQA(kt_, dd, q_) do {                                                  \
    const int row_ = (q_) * 64 + srl;                                          \
    gload_lds16(W + (size_t)(m0 + row_) * 1024 + (kt_) * 64 + sxk,             \
                smem + (dd) * 16384 + (q_) * 4096 + tid * 8);                  \
  } while (0)

#define SQB(kt_, dd, q_) do {                                                  \
    const int row_ = (q_) * 64 + srl;                                          \
    const int kg_  = (kt_) * 64 + sxk;                                         \
    const int rsh_ = (kg_ >= 512) ? dcap : 0;                                  \
    gload_lds16(Xt + xtb + (size_t)(DPAD + t0 + row_ - rsh_) * C_ + (kg_ & 511), \
                smem + 32768 + (dd) * 16384 + (q_) * 4096 + tid * 8);          \
  } while (0)

#define LDA_(Ab_, f_, kk_) \
  (*(const bf16x8*)((Ab_) + (size_t)(wm * 128 + (f_) * 16 + lp) * 64 + ((((kk_) * 4 + lg) ^ lx) << 3)))
#define LDB_(Bb_, j_, kk_) \
  (*(const bf16x8*)((Bb_) + (size_t)(wn * 64 + (j_) * 16 + lp) * 64 + ((((kk_) * 4 + lg) ^ lx) << 3)))

#define PH(dd, p_, WAITS, STAGES) do {                                         \
    WAITS;                                                                     \
    __builtin_amdgcn_sched_barrier(0);                                         \
    __builtin_amdgcn_s_barrier();                                              \
    __builtin_amdgcn_sched_barrier(0);                                         \
    const u16* Ab_ = smem + (dd) * 16384;                                      \
    const u16* Bb_ = smem + 32768 + (dd) * 16384;                              \
    if ((p_) == 0) {                                                           \
      _Pragma("unroll") for (int j_ = 0; j_ < 4; ++j_) {                       \
        bfr[j_][0] = LDB_(Bb_, j_, 0); bfr[j_][1] = LDB_(Bb_, j_, 1);          \
      }                                                                        \
    }                                                                          \
    bf16x8 a00 = LDA_(Ab_, 2 * (p_), 0),     a01 = LDA_(Ab_, 2 * (p_), 1);     \
    bf16x8 a10 = LDA_(Ab_, 2 * (p_) + 1, 0), a11 = LDA_(Ab_, 2 * (p_) + 1, 1); \
    STAGES;                                                                    \
    __builtin_amdgcn_s_setprio(1);                                             \
    _Pragma("unroll") for (int j_ = 0; j_ < 4; ++j_) {                         \
      acc[2*(p_)][j_]   = __builtin_amdgcn_mfma_f32_16x16x32_bf16(a00, bfr[j_][0], acc[2*(p_)][j_],   0, 0, 0); \
      acc[2*(p_)][j_]   = __builtin_amdgcn_mfma_f32_16x16x32_bf16(a01, bfr[j_][1], acc[2*(p_)][j_],   0, 0, 0); \
      acc[2*(p_)+1][j_] = __builtin_amdgcn_mfma_f32_16x16x32_bf16(a10, bfr[j_][0], acc[2*(p_)+1][j_], 0, 0, 0); \
      acc[2*(p_)+1][j_] = __builtin_amdgcn_mfma_f32_16x16x32_bf16(a11, bfr[j_][1], acc[2*(p_)+1][j_], 0, 0, 0); \
    }                                                                          \
    __builtin_amdgcn_s_setprio(0);                                             \
  } while (0)

#define VMW(n_) asm volatile("s_waitcnt vmcnt(" #n_ ")" ::: "memory")

  bf16x8 bfr[4][2];

  // prologue: stage tile 0 into buf 0 (exact steady-state issue order)
  SQB(0, 0, 0); SQB(0, 0, 1); SQB(0, 0, 2); SQB(0, 0, 3);
  SQA(0, 0, 0); SQA(0, 0, 2); SQA(0, 0, 1); SQA(0, 0, 3);

  for (int t = 0; t < 15; ++t) {
    const int dd = t & 1, de = dd ^ 1;
    PH(dd, 0, VMW(2), { SQB(t + 1, de, 0); SQB(t + 1, de, 1); });
    PH(dd, 1,       , { SQB(t + 1, de, 2); SQB(t + 1, de, 3); });
    PH(dd, 2, VMW(4), { SQA(t + 1, de, 0); SQA(t + 1, de, 2); });
    PH(dd, 3,       , { SQA(t + 1, de, 1); SQA(t + 1, de, 3); });
  }
  // t = 15 peeled (no staging; final waits drain)
  PH(1, 0, VMW(2), );
  PH(1, 1,       , );
  PH(1, 2, VMW(0), );
  PH(1, 3,       , );

  // epilogue: rows R..R+3 = (filter c0, gate c0, filter c0+1, gate c0+1)
  const int g = lane >> 4, p = lane & 15;
#pragma unroll
  for (int i = 0; i < 8; ++i) {
    const int R = m0 + wm * 128 + i * 16 + (g << 2);
    const float bi0 = b1[R], bi1 = b1[R + 1], bi2 = b1[R + 2], bi3 = b1[R + 3];
    const int c0 = R >> 1;
#pragma unroll
    for (int j = 0; j < 4; ++j) {
      const int ttc = t0 + wn * 64 + j * 16 + p;
      f32x4 v = acc[i][j];
      float z0 = tanh_(v[0] + bi0) * sigm_(v[1] + bi1);
      float z1 = tanh_(v[2] + bi2) * sigm_(v[3] + bi3);
      u32 pk = (u32)f2bf(z0) | ((u32)f2bf(z1) << 16);
      *(u32*)(Zt + (size_t)(b * T_ + ttc) * C_ + c0) = pk;
    }
  }
#undef SQA
#undef SQB
#undef LDA_
#undef LDB_
#undef PH
#undef VMW
}

// ---------------- GEMM2: [768x512] x z + residual/skip epilogue ----------------
// k-loop: proven drain structure. Epilogue: per-wave LDS transpose in disjoint
// region -> f32x4 coalesced x-loads / out-stores along t.
__global__ __launch_bounds__(256, 4) void gemm2_kernel(
    const u16* __restrict__ W2, const u16* __restrict__ Zt,
    const float* __restrict__ b2, const float* __restrict__ x,
    float* __restrict__ out)
{
  __shared__ __align__(16) u16 As[128 * 32];
  __shared__ __align__(16) u16 Bs[128 * 32];
  __shared__ __align__(16) float fstall[4 * 1088];   // 4 waves x 16x68 padded
  const int tid = threadIdx.x;
  const int lane = tid & 63, wave = tid >> 6;
  const int wm = wave >> 1, wn = wave & 1;

  const int bid = blockIdx.x;
  const int xcd = bid & 7;
  const int idx = bid >> 3;            // 0..383
  const int mt  = idx % 6;
  const int nt  = (xcd << 6) + idx / 6;
  const int m0 = mt * 128;
  const int n0g = nt * 128;
  const int b = n0g >> 13, t0 = n0g & (T_ - 1);
  const int srow = tid >> 2;
  const int skk  = (tid & 3) * 8;

  f32x4 acc[4][4];
#pragma unroll
  for (int i = 0; i < 4; ++i)
#pragma unroll
    for (int j = 0; j < 4; ++j) acc[i][j] = (f32x4){0.f, 0.f, 0.f, 0.f};

  const int aoff = (wm * 64 + (lane & 15)) * 32 + (lane >> 4) * 8;
  const int boff = (wn * 64 + (lane & 15)) * 32 + (lane >> 4) * 8;
  const size_t ztb = (size_t)b * T_ * C_;

  for (int kc = 0; kc < 16; ++kc) {
    const int k = kc * 32 + skk;        // 0..511
    const u16* gA = W2 + (size_t)(m0 + srow) * 512 + k;
    const u16* gB = Zt + ztb + (size_t)(t0 + srow) * C_ + k;
    gload_lds16(gA,            As + tid * 8);
    gload_lds16(gA + 64 * 512, As + 2048 + tid * 8);
    gload_lds16(gB,            Bs + tid * 8);
    gload_lds16(gB + 64 * C_,  Bs + 2048 + tid * 8);
    asm volatile("s_waitcnt vmcnt(0)" ::: "memory");
    __syncthreads();
    bf16x8 af[4], bfr[4];
#pragma unroll
    for (int i = 0; i < 4; ++i) af[i]  = *(const bf16x8*)(As + aoff + i * 512);
#pragma unroll
    for (int j = 0; j < 4; ++j) bfr[j] = *(const bf16x8*)(Bs + boff + j * 512);
#pragma unroll
    for (int i = 0; i < 4; ++i)
#pragma unroll
      for (int j = 0; j < 4; ++j)
        acc[i][j] = __builtin_amdgcn_mfma_f32_16x16x32_bf16(af[i], bfr[j], acc[i][j], 0, 0, 0);
    __syncthreads();
  }

  // ---- coalesced epilogue: per-wave private LDS transpose of 16x64 quadrants ----
  float* const fst = fstall + wave * 1088;         // 16 rows x 68 (padded)
  const int g = lane >> 4, p = lane & 15;
  const bool isres = (m0 < 512);

#pragma unroll
  for (int i = 0; i < 4; ++i) {
#pragma unroll
    for (int j = 0; j < 4; ++j)
#pragma unroll
      for (int r = 0; r < 4; ++r)
        fst[(g * 4 + r) * 68 + j * 16 + p] = acc[i][j][r];
#pragma unroll
    for (int q = 0; q < 4; ++q) {
      const int lrow = q * 4 + g;                  // 0..15
      const int row = m0 + wm * 64 + i * 16 + lrow;
      const int t = t0 + wn * 64 + p * 4;
      f32x4 v = *(const f32x4*)&fst[lrow * 68 + p * 4];
      const float bias = b2[row];
      f32x4 res;
      if (isres) {
        const size_t o = ((size_t)(b * 512 + row)) * T_ + t;
        f32x4 xv = *(const f32x4*)(x + o);
#pragma unroll
        for (int e = 0; e < 4; ++e)
          res[e] = (xv[e] + v[e] + bias) * 0.70710678118654752f;
        *(f32x4*)(out + o) = res;
      } else {
        const size_t o = (size_t)33554432 + ((size_t)(b * 256 + (row - 512))) * T_ + t;
#pragma unroll
        for (int e = 0; e < 4; ++e)
          res[e] = v[e] + bias;
        *(f32x4*)(out + o) = res;
      }
    }
  }
}

extern "C" void kernel_launch(void* const* d_in, const int* in_sizes, int n_in,
                              void* d_out, int out_size, void* d_ws, size_t ws_size,
                              hipStream_t stream) {
  const float* x  = (const float*)d_in[0];
  const float* fw = (const float*)d_in[1];
  const float* fb = (const float*)d_in[2];
  const float* gw = (const float*)d_in[3];
  const float* gb = (const float*)d_in[4];
  const float* rw = (const float*)d_in[5];
  const float* rb = (const float*)d_in[6];
  const float* sw = (const float*)d_in[7];
  const float* sb = (const float*)d_in[8];
  const int* dil  = (const int*)d_in[9];

  char* ws = (char*)d_ws;
  u16*   Wbig = (u16*)(ws + OFF_WBIG);
  u16*   W2   = (u16*)(ws + OFF_W2);
  float* b1   = (float*)(ws + OFF_B1);
  float* b2   = (float*)(ws + OFF_B2);
  u16*   Xt   = (u16*)(ws + OFF_XT);
  u16*   Zt   = (u16*)(ws + OFF_ZT);
  float* out  = (float*)d_out;

  hipLaunchKernelGGL(pack_kernel, dim3(5767), dim3(256), 0, stream,
                     fw, fb, gw, gb, rw, rb, sw, sb, Wbig, W2, b1, b2, Xt);
  hipLaunchKernelGGL(transpose_kernel, dim3(8192), dim3(256), 0, stream, x, Xt);
  hipLaunchKernelGGL(gemm1_kernel, dim3(1024), dim3(512), 0, stream, Wbig, Xt, b1, Zt, dil);
  hipLaunchKernelGGL(gemm2_kernel, dim3(3072), dim3(256), 0, stream, W2, Zt, b2, x, out);
}